// Round 23
// baseline (277.638 us; speedup 1.0000x reference)
//
#include <hip/hip_runtime.h>

#define Bc 16
#define Sc 512
#define Dc 1024
#define Hc 16
#define DHc 64

#define AS1 __attribute__((address_space(1)))
#define AS3 __attribute__((address_space(3)))

typedef __attribute__((ext_vector_type(8))) __bf16 bf16x8;
typedef __attribute__((ext_vector_type(4))) float f32x4;
typedef __attribute__((ext_vector_type(8))) unsigned short ushort8;

static __device__ __forceinline__ unsigned short f2bf(float f) {
  unsigned int u = __builtin_bit_cast(unsigned int, f);
  unsigned int r = (u + 0x7fffu + ((u >> 16) & 1u)) >> 16;  // RNE
  return (unsigned short)r;
}
static __device__ __forceinline__ float bf2f(unsigned short u) {
  unsigned int x = ((unsigned int)u) << 16;
  return __builtin_bit_cast(float, x);
}

// ---------------------------------------------------------------------------
// Merged prep: [0,8192) pos_add ; [8192,8960) W transpose ; [8960,8992) WspeT ;
// [8992,11040) spe int32 -> uint16 pack
// ---------------------------------------------------------------------------
__global__ __launch_bounds__(256) void k_prep(
    const float* __restrict__ hidden, const int* __restrict__ ind,
    const int* __restrict__ outd, const float* __restrict__ Win,
    const float* __restrict__ Wout, const float* __restrict__ Wq,
    const float* __restrict__ Wk, const float* __restrict__ Wv,
    const float* __restrict__ Wspe, const int* __restrict__ spe,
    unsigned short* __restrict__ hbf, unsigned short* __restrict__ Wtq,
    unsigned short* __restrict__ Wtk, unsigned short* __restrict__ Wtv,
    float* __restrict__ WspeT, unsigned short* __restrict__ spe16) {
  __shared__ float tile[64][65];
  int blk = blockIdx.x;
  int t = threadIdx.x;
  if (blk < 8192) {
    int row = blk;
    int id = ind[row], od = outd[row];
    float fi = (id != 0) ? 1.f : 0.f;
    float fo = (od != 0) ? 1.f : 0.f;
    float4 a = ((const float4*)(hidden + (size_t)row * Dc))[t];
    float4 x = ((const float4*)(Win + (size_t)id * Dc))[t];
    float4 y = ((const float4*)(Wout + (size_t)od * Dc))[t];
    ushort4 r;
    r.x = f2bf(a.x + fi * x.x + fo * y.x);
    r.y = f2bf(a.y + fi * x.y + fo * y.y);
    r.z = f2bf(a.z + fi * x.z + fo * y.z);
    r.w = f2bf(a.w + fi * x.w + fo * y.w);
    ((ushort4*)(hbf + (size_t)row * Dc))[t] = r;
  } else if (blk < 8960) {
    int f = blk - 8192;
    int z = f >> 8, rem = f & 255;
    int ky = rem >> 4, nx = rem & 15;
    const float* W = z == 0 ? Wq : z == 1 ? Wk : Wv;
    unsigned short* Wt = z == 0 ? Wtq : z == 1 ? Wtk : Wtv;
    int k0 = ky * 64, n0 = nx * 64;
    int r = t >> 4, c4 = (t & 15) * 4;
    for (int rr = r; rr < 64; rr += 16) {
      float4 v = *(const float4*)(W + (size_t)(k0 + rr) * Dc + n0 + c4);
      tile[rr][c4 + 0] = v.x;
      tile[rr][c4 + 1] = v.y;
      tile[rr][c4 + 2] = v.z;
      tile[rr][c4 + 3] = v.w;
    }
    __syncthreads();
    for (int rr = r; rr < 64; rr += 16) {
      ushort4 o;
      o.x = f2bf(tile[c4 + 0][rr]);
      o.y = f2bf(tile[c4 + 1][rr]);
      o.z = f2bf(tile[c4 + 2][rr]);
      o.w = f2bf(tile[c4 + 3][rr]);
      *(ushort4*)(Wt + (size_t)(n0 + rr) * Dc + k0 + c4) = o;
    }
  } else if (blk < 8992) {
    int idx = (blk - 8960) * 256 + t;
    int h = idx >> 9, i = idx & 511;
    WspeT[idx] = Wspe[i * Hc + h];
  } else {
    size_t base = (size_t)(blk - 8992) * 2048 + t * 8;
    int4 a = *(const int4*)(spe + base);
    int4 c = *(const int4*)(spe + base + 4);
    ushort8 o;
    o[0] = (unsigned short)a.x; o[1] = (unsigned short)a.y;
    o[2] = (unsigned short)a.z; o[3] = (unsigned short)a.w;
    o[4] = (unsigned short)c.x; o[5] = (unsigned short)c.y;
    o[6] = (unsigned short)c.z; o[7] = (unsigned short)c.w;
    *(ushort8*)(spe16 + base) = o;
  }
}

// ---------------------------------------------------------------------------
// QKV projections, bf16 MFMA. BM=256 (A-refetch halved: staging traffic
// 768 -> 576 MB), BN=128, BK=64 via split 32-wide LDS halves. 4 waves; wave
// owns 64 rows x 128 cols (acc[4][8]). Q pre-scaled by 1/8. V transposed out.
// ---------------------------------------------------------------------------
__global__ __launch_bounds__(256) void k_gemm_mfma(
    const unsigned short* __restrict__ hbf,
    const unsigned short* __restrict__ Wtq, const float* __restrict__ bq,
    const unsigned short* __restrict__ Wtk, const float* __restrict__ bk,
    const unsigned short* __restrict__ Wtv, const float* __restrict__ bv,
    unsigned short* __restrict__ Qo, unsigned short* __restrict__ Ko,
    unsigned short* __restrict__ Vt) {
  int zsel = blockIdx.z;
  const unsigned short* Wt;
  const float* bias;
  if (zsel == 0) { Wt = Wtq; bias = bq; }
  else if (zsel == 1) { Wt = Wtk; bias = bk; }
  else { Wt = Wtv; bias = bv; }

  __shared__ __align__(16) unsigned short As0[256 * 32];  // 16 KB
  __shared__ __align__(16) unsigned short As1[256 * 32];  // 16 KB
  __shared__ __align__(16) unsigned short Bs0[128 * 32];  // 8 KB
  __shared__ __align__(16) unsigned short Bs1[128 * 32];  // 8 KB

  int tid = threadIdx.x, lane = tid & 63, wave = tid >> 6;
  int m0 = blockIdx.y * 256, n0 = blockIdx.x * 128;

  f32x4 acc[4][8] = {};

  int srow = lane >> 2;
  int skb = (lane & 3) * 8;
  const unsigned short* gA = hbf + (size_t)(m0 + srow) * Dc + skb;
  const unsigned short* gB = Wt + (size_t)(n0 + srow) * Dc + skb;

  int fr = lane & 15, kg = (lane >> 4) * 8;

  for (int k0 = 0; k0 < Dc; k0 += 64) {
    // stage A: 16 chunks of 16 rows (4 per wave); B: 8 chunks (2 per wave)
#pragma unroll
    for (int cc = 0; cc < 4; ++cc) {
      int c = wave + cc * 4;
      __builtin_amdgcn_global_load_lds(
          (const AS1 void*)(gA + (size_t)c * 16 * Dc + k0),
          (AS3 void*)(As0 + c * 16 * 32), 16, 0, 0);
      __builtin_amdgcn_global_load_lds(
          (const AS1 void*)(gA + (size_t)c * 16 * Dc + k0 + 32),
          (AS3 void*)(As1 + c * 16 * 32), 16, 0, 0);
    }
#pragma unroll
    for (int cc = 0; cc < 2; ++cc) {
      int c = wave + cc * 4;
      __builtin_amdgcn_global_load_lds(
          (const AS1 void*)(gB + (size_t)c * 16 * Dc + k0),
          (AS3 void*)(Bs0 + c * 16 * 32), 16, 0, 0);
      __builtin_amdgcn_global_load_lds(
          (const AS1 void*)(gB + (size_t)c * 16 * Dc + k0 + 32),
          (AS3 void*)(Bs1 + c * 16 * 32), 16, 0, 0);
    }
    __syncthreads();

    bf16x8 af[4][2], bfr[8][2];
#pragma unroll
    for (int m = 0; m < 4; ++m) {
      af[m][0] = *(const bf16x8*)(As0 + (wave * 64 + m * 16 + fr) * 32 + kg);
      af[m][1] = *(const bf16x8*)(As1 + (wave * 64 + m * 16 + fr) * 32 + kg);
    }
#pragma unroll
    for (int n = 0; n < 8; ++n) {
      bfr[n][0] = *(const bf16x8*)(Bs0 + (n * 16 + fr) * 32 + kg);
      bfr[n][1] = *(const bf16x8*)(Bs1 + (n * 16 + fr) * 32 + kg);
    }
#pragma unroll
    for (int m = 0; m < 4; ++m)
#pragma unroll
      for (int n = 0; n < 8; ++n) {
        acc[m][n] = __builtin_amdgcn_mfma_f32_16x16x32_bf16(af[m][0], bfr[n][0], acc[m][n], 0, 0, 0);
        acc[m][n] = __builtin_amdgcn_mfma_f32_16x16x32_bf16(af[m][1], bfr[n][1], acc[m][n], 0, 0, 0);
      }
    __syncthreads();
  }

  int fq = lane >> 4;
  if (zsel < 2) {
    unsigned short* C = (zsel == 0) ? Qo : Ko;
    float scale = (zsel == 0) ? 0.125f : 1.f;  // fold 1/sqrt(64) into Q (exact)
#pragma unroll
    for (int m = 0; m < 4; ++m) {
#pragma unroll
      for (int n = 0; n < 8; ++n) {
        int col = n0 + n * 16 + fr;
        float bb = bias[col];
#pragma unroll
        for (int r = 0; r < 4; ++r) {
          int row = m0 + wave * 64 + m * 16 + fq * 4 + r;
          C[(size_t)row * Dc + col] = f2bf((acc[m][n][r] + bb) * scale);
        }
      }
    }
  } else {
#pragma unroll
    for (int m = 0; m < 4; ++m) {
#pragma unroll
      for (int n = 0; n < 8; ++n) {
        int col = n0 + n * 16 + fr;
        int hh = col >> 6, dh = col & 63;
        float bb = bias[col];
        int row = m0 + wave * 64 + m * 16 + fq * 4;
        int bb_ = row >> 9, ss = row & 511;
        ushort4 pk;
        pk.x = f2bf(acc[m][n][0] + bb);
        pk.y = f2bf(acc[m][n][1] + bb);
        pk.z = f2bf(acc[m][n][2] + bb);
        pk.w = f2bf(acc[m][n][3] + bb);
        *(ushort4*)(Vt + ((size_t)(bb_ * Hc + hh) * DHc + dh) * Sc + ss) = pk;
      }
    }
  }
}

// ---------------------------------------------------------------------------
// Fused attention (round-22 best config, unchanged): block = (b, h, 16
// q-rows); 4 waves; 18752 B LDS -> 8 blocks/CU. L2-capacity swizzle;
// phase rotation; swapped-operand MFMAs; no-max softmax; spe uint16;
// contiguous 1KB/wave probs NT bursts inside PV loop; ctx NT store.
// ---------------------------------------------------------------------------
#define SWB 520
__global__ __launch_bounds__(256, 8) void k_attn(
    const unsigned short* __restrict__ Qb, const unsigned short* __restrict__ Kb,
    const unsigned short* __restrict__ Vt, const unsigned short* __restrict__ spe16,
    const float* __restrict__ WspeT, const float* __restrict__ mask,
    float* __restrict__ probs, float* __restrict__ ctx) {
  extern __shared__ char smem[];
  unsigned short* S = (unsigned short*)smem;     // 16*520*2 = 16640
  float* Wb = (float*)(smem + 16640);            // 2048
  float* Rinv = (float*)(smem + 16640 + 2048);   // 64

  int tid = threadIdx.x, lane = tid & 63, w = tid >> 6;
  int fr = lane & 15, fq = lane >> 4, kg8 = fq * 8;

  // L2-capacity swizzle: xcd = (b&3)*2 + (h>>3); h-innermost within idx.
  int flat = blockIdx.x;
  int xcd = flat & 7, idx = flat >> 3;
  int b = (idx >> 8) * 4 + (xcd >> 1);
  int h = (xcd & 1) * 8 + (idx & 7);
  int qt = (idx >> 3) & 31;
  int q0 = qt * 16;
  int rot = idx & 7;  // phase rotation (decorrelates neighbors)

  // coalesced per-head bias row
  for (int i = tid; i < 512; i += 256) Wb[i] = WspeT[h * 512 + i];

  // hoisted spe (uint16) + mask loads — latency covered by QK^T below
  const unsigned short* spp0 =
      spe16 + (size_t)(b * Sc + q0 + w * 4) * Sc + lane * 8;
  ushort8 iv0 = *(const ushort8*)(spp0);
  ushort8 iv1 = *(const ushort8*)(spp0 + Sc);
  ushort8 iv2 = *(const ushort8*)(spp0 + 2 * Sc);
  ushort8 iv3 = *(const ushort8*)(spp0 + 3 * Sc);
  float4 mk0 = *(const float4*)(mask + b * Sc + lane * 8);
  float4 mk1 = *(const float4*)(mask + b * Sc + lane * 8 + 4);

  // Q fragments (pre-scaled by 1/8) in registers — B-operand of swapped QK^T
  const unsigned short* qbase = Qb + (size_t)(b * Sc + q0) * Dc + h * DHc;
  bf16x8 af0 = *(const bf16x8*)(qbase + (size_t)fr * Dc + kg8);
  bf16x8 af1 = *(const bf16x8*)(qbase + (size_t)fr * Dc + 32 + kg8);

  // ---- QK^T (swapped, rotated): acc = K-tile x Q -> D[k][q] ----
  const unsigned short* kptr =
      Kb + (size_t)(b * Sc + w * 16 + fr) * Dc + h * DHc;
  bf16x8 kfA0 = *(const bf16x8*)(kptr + (size_t)rot * 64 * Dc + kg8);
  bf16x8 kfA1 = *(const bf16x8*)(kptr + (size_t)rot * 64 * Dc + 32 + kg8);
#pragma unroll
  for (int i = 0; i < 8; ++i) {
    int it = (i + rot) & 7;
    bf16x8 kfB0, kfB1;
    if (i < 7) {
      int itn = (i + 1 + rot) & 7;
      const unsigned short* np = kptr + (size_t)itn * 64 * Dc;
      kfB0 = *(const bf16x8*)(np + kg8);
      kfB1 = *(const bf16x8*)(np + 32 + kg8);
    }
    f32x4 acc = {};
    __builtin_amdgcn_s_setprio(1);
    acc = __builtin_amdgcn_mfma_f32_16x16x32_bf16(kfA0, af0, acc, 0, 0, 0);
    acc = __builtin_amdgcn_mfma_f32_16x16x32_bf16(kfA1, af1, acc, 0, 0, 0);
    __builtin_amdgcn_s_setprio(0);
    ushort4 pk;
    pk.x = f2bf(acc[0]); pk.y = f2bf(acc[1]);
    pk.z = f2bf(acc[2]); pk.w = f2bf(acc[3]);
    *(ushort4*)(S + fr * SWB + it * 64 + w * 16 + fq * 4) = pk;
    kfA0 = kfB0; kfA1 = kfB1;
  }
  __syncthreads();  // barrier 1: S complete, Wb ready

  // ---- softmax (no max-subtract) ----
  {
#pragma unroll
    for (int r4 = 0; r4 < 4; ++r4) {
      int row = w * 4 + r4;
      ushort8 iv = (r4 == 0) ? iv0 : (r4 == 1) ? iv1 : (r4 == 2) ? iv2 : iv3;
      ushort8 sv = *(const ushort8*)(S + row * SWB + lane * 8);
      float e0 = __expf(bf2f(sv[0]) + Wb[iv[0]] + mk0.x);
      float e1 = __expf(bf2f(sv[1]) + Wb[iv[1]] + mk0.y);
      float e2 = __expf(bf2f(sv[2]) + Wb[iv[2]] + mk0.z);
      float e3 = __expf(bf2f(sv[3]) + Wb[iv[3]] + mk0.w);
      float e4 = __expf(bf2f(sv[4]) + Wb[iv[4]] + mk1.x);
      float e5 = __expf(bf2f(sv[5]) + Wb[iv[5]] + mk1.y);
      float e6 = __expf(bf2f(sv[6]) + Wb[iv[6]] + mk1.z);
      float e7 = __expf(bf2f(sv[7]) + Wb[iv[7]] + mk1.w);
      float sum = e0 + e1 + e2 + e3 + e4 + e5 + e6 + e7;
#pragma unroll
      for (int o = 32; o; o >>= 1) sum += __shfl_xor(sum, o);
      float rinv = 1.f / sum;
      ushort8 ev;
      ev[0] = f2bf(e0); ev[1] = f2bf(e1); ev[2] = f2bf(e2); ev[3] = f2bf(e3);
      ev[4] = f2bf(e4); ev[5] = f2bf(e5); ev[6] = f2bf(e6); ev[7] = f2bf(e7);
      *(ushort8*)(S + row * SWB + lane * 8) = ev;
      if (lane == 0) Rinv[row] = rinv;
    }
  }
  __syncthreads();  // barrier 2: exp(S) bf16, Rinv complete

  // ---- PV (swapped, rotated) + 2-full-row probs writes per iteration ----
  const unsigned short* vptr =
      Vt + ((size_t)(b * Hc + h) * DHc + w * 16 + fr) * Sc;
  float* pbase = probs + (size_t)((b * Hc + h) * Sc + q0) * Sc;
  int prow_half = tid >> 7;          // 0..1 (which of the 2 rows this it)
  int pcol = (tid & 127) * 4;        // 0..508
  f32x4 pacc0 = {}, pacc1 = {};
  bf16x8 vfA0 = *(const bf16x8*)(vptr + rot * 64 + kg8);
  bf16x8 vfA1 = *(const bf16x8*)(vptr + rot * 64 + 32 + kg8);
#pragma unroll
  for (int i = 0; i < 8; ++i) {
    int it = (i + rot) & 7;
    bf16x8 vfB0, vfB1;
    if (i < 7) {
      int itn = (i + 1 + rot) & 7;
      vfB0 = *(const bf16x8*)(vptr + itn * 64 + kg8);
      vfB1 = *(const bf16x8*)(vptr + itn * 64 + 32 + kg8);
    }
    {  // probs: 2 full rows; each wave writes 1 KB contiguous (NT)
      int row = i * 2 + prow_half;
      ushort4 sv = *(const ushort4*)(S + row * SWB + pcol);
      float rv = Rinv[row];
      f32x4 e;
      e[0] = bf2f(sv.x) * rv; e[1] = bf2f(sv.y) * rv;
      e[2] = bf2f(sv.z) * rv; e[3] = bf2f(sv.w) * rv;
      __builtin_nontemporal_store(e, (f32x4*)(pbase + (size_t)row * Sc + pcol));
    }
    bf16x8 pfr0 = *(const bf16x8*)(S + fr * SWB + it * 64 + kg8);
    bf16x8 pfr1 = *(const bf16x8*)(S + fr * SWB + it * 64 + 32 + kg8);
    __builtin_amdgcn_s_setprio(1);
    pacc0 = __builtin_amdgcn_mfma_f32_16x16x32_bf16(vfA0, pfr0, pacc0, 0, 0, 0);
    pacc1 = __builtin_amdgcn_mfma_f32_16x16x32_bf16(vfA1, pfr1, pacc1, 0, 0, 0);
    __builtin_amdgcn_s_setprio(0);
    vfA0 = vfB0; vfA1 = vfB1;
  }

  // ---- ctx epilogue: lane = (q=fr, dh w*16+fq*4..+3) -> one 16B NT store ----
  {
    float rv = Rinv[fr];
    f32x4 o;
    o[0] = (pacc0[0] + pacc1[0]) * rv;
    o[1] = (pacc0[1] + pacc1[1]) * rv;
    o[2] = (pacc0[2] + pacc1[2]) * rv;
    o[3] = (pacc0[3] + pacc1[3]) * rv;
    __builtin_nontemporal_store(
        o, (f32x4*)(ctx + (size_t)(b * Sc + q0 + fr) * Dc + h * DHc + w * 16 + fq * 4));
  }
}

extern "C" void kernel_launch(void* const* d_in, const int* in_sizes, int n_in,
                              void* d_out, int out_size, void* d_ws, size_t ws_size,
                              hipStream_t stream) {
  const float* hidden = (const float*)d_in[0];
  const float* amask = (const float*)d_in[1];
  const int* ind = (const int*)d_in[3];
  const int* outd = (const int*)d_in[4];
  const int* spe = (const int*)d_in[5];
  const float* Wq = (const float*)d_in[8];
  const float* bq = (const float*)d_in[9];
  const float* Wk = (const float*)d_in[10];
  const float* bk = (const float*)d_in[11];
  const float* Wv = (const float*)d_in[12];
  const float* bv = (const float*)d_in[13];
  const float* Win = (const float*)d_in[14];
  const float* Wout = (const float*)d_in[15];
  const float* Wspe = (const float*)d_in[16];

  char* ws = (char*)d_ws;
  const size_t BSD = (size_t)Bc * Sc * Dc;
  unsigned short* hbf = (unsigned short*)ws;                    // 16 MB
  unsigned short* Wtq = (unsigned short*)(ws + 16u * 1048576);  // 2 MB
  unsigned short* Wtk = (unsigned short*)(ws + 18u * 1048576);  // 2 MB
  unsigned short* Wtv = (unsigned short*)(ws + 20u * 1048576);  // 2 MB
  float* WspeT = (float*)(ws + 22u * 1048576);                  // 32 KB
  unsigned short* Qb = (unsigned short*)(ws + 24u * 1048576);   // 16 MB
  unsigned short* Kb = (unsigned short*)(ws + 40u * 1048576);   // 16 MB
  unsigned short* Vt = (unsigned short*)(ws + 56u * 1048576);   // 16 MB (transposed)
  unsigned short* spe16 = (unsigned short*)(ws + 72u * 1048576);  // 8.4 MB
  float* ctx = (float*)d_out;
  float* probs = (float*)d_out + BSD;

  (void)hipFuncSetAttribute((const void*)k_attn,
                            hipFuncAttributeMaxDynamicSharedMemorySize, 18752);

  k_prep<<<dim3(11040), 256, 0, stream>>>(hidden, ind, outd, Win, Wout, Wq, Wk,
                                          Wv, Wspe, spe, hbf, Wtq, Wtk, Wtv,
                                          WspeT, spe16);
  k_gemm_mfma<<<dim3(8, 32, 3), 256, 0, stream>>>(hbf, Wtq, bq, Wtk, bk, Wtv, bv, Qb, Kb, Vt);
  k_attn<<<dim3(8192), 256, 18752, stream>>>(Qb, Kb, Vt, spe16, WspeT, amask, probs, ctx);
}

// Round 24
// 227.517 us; speedup vs baseline: 1.2203x; 1.2203x over previous
//
#include <hip/hip_runtime.h>

#define Bc 16
#define Sc 512
#define Dc 1024
#define Hc 16
#define DHc 64

#define AS1 __attribute__((address_space(1)))
#define AS3 __attribute__((address_space(3)))

typedef __attribute__((ext_vector_type(8))) __bf16 bf16x8;
typedef __attribute__((ext_vector_type(4))) float f32x4;
typedef __attribute__((ext_vector_type(8))) unsigned short ushort8;

static __device__ __forceinline__ unsigned short f2bf(float f) {
  unsigned int u = __builtin_bit_cast(unsigned int, f);
  unsigned int r = (u + 0x7fffu + ((u >> 16) & 1u)) >> 16;  // RNE
  return (unsigned short)r;
}
static __device__ __forceinline__ float bf2f(unsigned short u) {
  unsigned int x = ((unsigned int)u) << 16;
  return __builtin_bit_cast(float, x);
}

// ---------------------------------------------------------------------------
// Merged prep: [0,8192) pos_add ; [8192,8960) W transpose ; [8960,8992) WspeT ;
// [8992,11040) spe int32 -> uint16 pack
// ---------------------------------------------------------------------------
__global__ __launch_bounds__(256) void k_prep(
    const float* __restrict__ hidden, const int* __restrict__ ind,
    const int* __restrict__ outd, const float* __restrict__ Win,
    const float* __restrict__ Wout, const float* __restrict__ Wq,
    const float* __restrict__ Wk, const float* __restrict__ Wv,
    const float* __restrict__ Wspe, const int* __restrict__ spe,
    unsigned short* __restrict__ hbf, unsigned short* __restrict__ Wtq,
    unsigned short* __restrict__ Wtk, unsigned short* __restrict__ Wtv,
    float* __restrict__ WspeT, unsigned short* __restrict__ spe16) {
  __shared__ float tile[64][65];
  int blk = blockIdx.x;
  int t = threadIdx.x;
  if (blk < 8192) {
    int row = blk;
    int id = ind[row], od = outd[row];
    float fi = (id != 0) ? 1.f : 0.f;
    float fo = (od != 0) ? 1.f : 0.f;
    float4 a = ((const float4*)(hidden + (size_t)row * Dc))[t];
    float4 x = ((const float4*)(Win + (size_t)id * Dc))[t];
    float4 y = ((const float4*)(Wout + (size_t)od * Dc))[t];
    ushort4 r;
    r.x = f2bf(a.x + fi * x.x + fo * y.x);
    r.y = f2bf(a.y + fi * x.y + fo * y.y);
    r.z = f2bf(a.z + fi * x.z + fo * y.z);
    r.w = f2bf(a.w + fi * x.w + fo * y.w);
    ((ushort4*)(hbf + (size_t)row * Dc))[t] = r;
  } else if (blk < 8960) {
    int f = blk - 8192;
    int z = f >> 8, rem = f & 255;
    int ky = rem >> 4, nx = rem & 15;
    const float* W = z == 0 ? Wq : z == 1 ? Wk : Wv;
    unsigned short* Wt = z == 0 ? Wtq : z == 1 ? Wtk : Wtv;
    int k0 = ky * 64, n0 = nx * 64;
    int r = t >> 4, c4 = (t & 15) * 4;
    for (int rr = r; rr < 64; rr += 16) {
      float4 v = *(const float4*)(W + (size_t)(k0 + rr) * Dc + n0 + c4);
      tile[rr][c4 + 0] = v.x;
      tile[rr][c4 + 1] = v.y;
      tile[rr][c4 + 2] = v.z;
      tile[rr][c4 + 3] = v.w;
    }
    __syncthreads();
    for (int rr = r; rr < 64; rr += 16) {
      ushort4 o;
      o.x = f2bf(tile[c4 + 0][rr]);
      o.y = f2bf(tile[c4 + 1][rr]);
      o.z = f2bf(tile[c4 + 2][rr]);
      o.w = f2bf(tile[c4 + 3][rr]);
      *(ushort4*)(Wt + (size_t)(n0 + rr) * Dc + k0 + c4) = o;
    }
  } else if (blk < 8992) {
    int idx = (blk - 8960) * 256 + t;
    int h = idx >> 9, i = idx & 511;
    WspeT[idx] = Wspe[i * Hc + h];
  } else {
    size_t base = (size_t)(blk - 8992) * 2048 + t * 8;
    int4 a = *(const int4*)(spe + base);
    int4 c = *(const int4*)(spe + base + 4);
    ushort8 o;
    o[0] = (unsigned short)a.x; o[1] = (unsigned short)a.y;
    o[2] = (unsigned short)a.z; o[3] = (unsigned short)a.w;
    o[4] = (unsigned short)c.x; o[5] = (unsigned short)c.y;
    o[6] = (unsigned short)c.z; o[7] = (unsigned short)c.w;
    *(ushort8*)(spe16 + base) = o;
  }
}

// ---------------------------------------------------------------------------
// QKV projections, bf16 MFMA, BK=64 via split 32-wide LDS halves (proven
// best; ~903 TF = m97-structure ceiling). Q pre-scaled by 1/8. Q,K
// row-major; V pre-transposed Vt[(b*16+h), dh, s].
// ---------------------------------------------------------------------------
__global__ __launch_bounds__(256) void k_gemm_mfma(
    const unsigned short* __restrict__ hbf,
    const unsigned short* __restrict__ Wtq, const float* __restrict__ bq,
    const unsigned short* __restrict__ Wtk, const float* __restrict__ bk,
    const unsigned short* __restrict__ Wtv, const float* __restrict__ bv,
    unsigned short* __restrict__ Qo, unsigned short* __restrict__ Ko,
    unsigned short* __restrict__ Vt) {
  int zsel = blockIdx.z;
  const unsigned short* Wt;
  const float* bias;
  if (zsel == 0) { Wt = Wtq; bias = bq; }
  else if (zsel == 1) { Wt = Wtk; bias = bk; }
  else { Wt = Wtv; bias = bv; }

  __shared__ __align__(16) unsigned short As0[128 * 32];
  __shared__ __align__(16) unsigned short As1[128 * 32];
  __shared__ __align__(16) unsigned short Bs0[128 * 32];
  __shared__ __align__(16) unsigned short Bs1[128 * 32];

  int tid = threadIdx.x, lane = tid & 63, wave = tid >> 6;
  int m0 = blockIdx.y * 128, n0 = blockIdx.x * 128;
  int wr = wave >> 1, wc = wave & 1;

  f32x4 acc[4][4] = {};

  int srow = lane >> 2;
  int skb = (lane & 3) * 8;
  const unsigned short* gA = hbf + (size_t)(m0 + srow) * Dc + skb;
  const unsigned short* gB = Wt + (size_t)(n0 + srow) * Dc + skb;

  int fr = lane & 15, kg = (lane >> 4) * 8;

  for (int k0 = 0; k0 < Dc; k0 += 64) {
#pragma unroll
    for (int cc = 0; cc < 2; ++cc) {
      int c = wave + cc * 4;  // 16-row chunk id
      __builtin_amdgcn_global_load_lds(
          (const AS1 void*)(gA + (size_t)c * 16 * Dc + k0),
          (AS3 void*)(As0 + c * 16 * 32), 16, 0, 0);
      __builtin_amdgcn_global_load_lds(
          (const AS1 void*)(gA + (size_t)c * 16 * Dc + k0 + 32),
          (AS3 void*)(As1 + c * 16 * 32), 16, 0, 0);
      __builtin_amdgcn_global_load_lds(
          (const AS1 void*)(gB + (size_t)c * 16 * Dc + k0),
          (AS3 void*)(Bs0 + c * 16 * 32), 16, 0, 0);
      __builtin_amdgcn_global_load_lds(
          (const AS1 void*)(gB + (size_t)c * 16 * Dc + k0 + 32),
          (AS3 void*)(Bs1 + c * 16 * 32), 16, 0, 0);
    }
    __syncthreads();

    bf16x8 af[4][2], bfr[4][2];
#pragma unroll
    for (int m = 0; m < 4; ++m) {
      af[m][0] = *(const bf16x8*)(As0 + (wr * 64 + m * 16 + fr) * 32 + kg);
      af[m][1] = *(const bf16x8*)(As1 + (wr * 64 + m * 16 + fr) * 32 + kg);
    }
#pragma unroll
    for (int n = 0; n < 4; ++n) {
      bfr[n][0] = *(const bf16x8*)(Bs0 + (wc * 64 + n * 16 + fr) * 32 + kg);
      bfr[n][1] = *(const bf16x8*)(Bs1 + (wc * 64 + n * 16 + fr) * 32 + kg);
    }
#pragma unroll
    for (int m = 0; m < 4; ++m)
#pragma unroll
      for (int n = 0; n < 4; ++n) {
        acc[m][n] = __builtin_amdgcn_mfma_f32_16x16x32_bf16(af[m][0], bfr[n][0], acc[m][n], 0, 0, 0);
        acc[m][n] = __builtin_amdgcn_mfma_f32_16x16x32_bf16(af[m][1], bfr[n][1], acc[m][n], 0, 0, 0);
      }
    __syncthreads();
  }

  int fq = lane >> 4;
  if (zsel < 2) {
    unsigned short* C = (zsel == 0) ? Qo : Ko;
    float scale = (zsel == 0) ? 0.125f : 1.f;  // fold 1/sqrt(64) into Q (exact)
#pragma unroll
    for (int m = 0; m < 4; ++m) {
#pragma unroll
      for (int n = 0; n < 4; ++n) {
        int col = n0 + wc * 64 + n * 16 + fr;
        float bb = bias[col];
#pragma unroll
        for (int r = 0; r < 4; ++r) {
          int row = m0 + wr * 64 + m * 16 + fq * 4 + r;
          C[(size_t)row * Dc + col] = f2bf((acc[m][n][r] + bb) * scale);
        }
      }
    }
  } else {
#pragma unroll
    for (int m = 0; m < 4; ++m) {
#pragma unroll
      for (int n = 0; n < 4; ++n) {
        int col = n0 + wc * 64 + n * 16 + fr;
        int hh = col >> 6, dh = col & 63;
        float bb = bias[col];
        int row = m0 + wr * 64 + m * 16 + fq * 4;
        int bb_ = row >> 9, ss = row & 511;
        ushort4 pk;
        pk.x = f2bf(acc[m][n][0] + bb);
        pk.y = f2bf(acc[m][n][1] + bb);
        pk.z = f2bf(acc[m][n][2] + bb);
        pk.w = f2bf(acc[m][n][3] + bb);
        *(ushort4*)(Vt + ((size_t)(bb_ * Hc + hh) * DHc + dh) * Sc + ss) = pk;
      }
    }
  }
}

// ---------------------------------------------------------------------------
// Fused attention (round-22 best config): block = (b, h, 16 q-rows); 4
// waves; 18752 B LDS -> 8 blocks/CU. L2-capacity swizzle; phase rotation;
// swapped-operand MFMAs; no-max softmax; spe uint16; contiguous 1KB/wave
// probs NT bursts inside PV loop; ctx NT store.
// ---------------------------------------------------------------------------
#define SWB 520
__global__ __launch_bounds__(256, 8) void k_attn(
    const unsigned short* __restrict__ Qb, const unsigned short* __restrict__ Kb,
    const unsigned short* __restrict__ Vt, const unsigned short* __restrict__ spe16,
    const float* __restrict__ WspeT, const float* __restrict__ mask,
    float* __restrict__ probs, float* __restrict__ ctx) {
  extern __shared__ char smem[];
  unsigned short* S = (unsigned short*)smem;     // 16*520*2 = 16640
  float* Wb = (float*)(smem + 16640);            // 2048
  float* Rinv = (float*)(smem + 16640 + 2048);   // 64

  int tid = threadIdx.x, lane = tid & 63, w = tid >> 6;
  int fr = lane & 15, fq = lane >> 4, kg8 = fq * 8;

  // L2-capacity swizzle: xcd = (b&3)*2 + (h>>3); h-innermost within idx.
  int flat = blockIdx.x;
  int xcd = flat & 7, idx = flat >> 3;
  int b = (idx >> 8) * 4 + (xcd >> 1);
  int h = (xcd & 1) * 8 + (idx & 7);
  int qt = (idx >> 3) & 31;
  int q0 = qt * 16;
  int rot = idx & 7;  // phase rotation (decorrelates neighbors)

  // coalesced per-head bias row
  for (int i = tid; i < 512; i += 256) Wb[i] = WspeT[h * 512 + i];

  // hoisted spe (uint16) + mask loads — latency covered by QK^T below
  const unsigned short* spp0 =
      spe16 + (size_t)(b * Sc + q0 + w * 4) * Sc + lane * 8;
  ushort8 iv0 = *(const ushort8*)(spp0);
  ushort8 iv1 = *(const ushort8*)(spp0 + Sc);
  ushort8 iv2 = *(const ushort8*)(spp0 + 2 * Sc);
  ushort8 iv3 = *(const ushort8*)(spp0 + 3 * Sc);
  float4 mk0 = *(const float4*)(mask + b * Sc + lane * 8);
  float4 mk1 = *(const float4*)(mask + b * Sc + lane * 8 + 4);

  // Q fragments (pre-scaled by 1/8) in registers — B-operand of swapped QK^T
  const unsigned short* qbase = Qb + (size_t)(b * Sc + q0) * Dc + h * DHc;
  bf16x8 af0 = *(const bf16x8*)(qbase + (size_t)fr * Dc + kg8);
  bf16x8 af1 = *(const bf16x8*)(qbase + (size_t)fr * Dc + 32 + kg8);

  // ---- QK^T (swapped, rotated): acc = K-tile x Q -> D[k][q] ----
  const unsigned short* kptr =
      Kb + (size_t)(b * Sc + w * 16 + fr) * Dc + h * DHc;
  bf16x8 kfA0 = *(const bf16x8*)(kptr + (size_t)rot * 64 * Dc + kg8);
  bf16x8 kfA1 = *(const bf16x8*)(kptr + (size_t)rot * 64 * Dc + 32 + kg8);
#pragma unroll
  for (int i = 0; i < 8; ++i) {
    int it = (i + rot) & 7;
    bf16x8 kfB0, kfB1;
    if (i < 7) {
      int itn = (i + 1 + rot) & 7;
      const unsigned short* np = kptr + (size_t)itn * 64 * Dc;
      kfB0 = *(const bf16x8*)(np + kg8);
      kfB1 = *(const bf16x8*)(np + 32 + kg8);
    }
    f32x4 acc = {};
    __builtin_amdgcn_s_setprio(1);
    acc = __builtin_amdgcn_mfma_f32_16x16x32_bf16(kfA0, af0, acc, 0, 0, 0);
    acc = __builtin_amdgcn_mfma_f32_16x16x32_bf16(kfA1, af1, acc, 0, 0, 0);
    __builtin_amdgcn_s_setprio(0);
    ushort4 pk;
    pk.x = f2bf(acc[0]); pk.y = f2bf(acc[1]);
    pk.z = f2bf(acc[2]); pk.w = f2bf(acc[3]);
    *(ushort4*)(S + fr * SWB + it * 64 + w * 16 + fq * 4) = pk;
    kfA0 = kfB0; kfA1 = kfB1;
  }
  __syncthreads();  // barrier 1: S complete, Wb ready

  // ---- softmax (no max-subtract) ----
  {
#pragma unroll
    for (int r4 = 0; r4 < 4; ++r4) {
      int row = w * 4 + r4;
      ushort8 iv = (r4 == 0) ? iv0 : (r4 == 1) ? iv1 : (r4 == 2) ? iv2 : iv3;
      ushort8 sv = *(const ushort8*)(S + row * SWB + lane * 8);
      float e0 = __expf(bf2f(sv[0]) + Wb[iv[0]] + mk0.x);
      float e1 = __expf(bf2f(sv[1]) + Wb[iv[1]] + mk0.y);
      float e2 = __expf(bf2f(sv[2]) + Wb[iv[2]] + mk0.z);
      float e3 = __expf(bf2f(sv[3]) + Wb[iv[3]] + mk0.w);
      float e4 = __expf(bf2f(sv[4]) + Wb[iv[4]] + mk1.x);
      float e5 = __expf(bf2f(sv[5]) + Wb[iv[5]] + mk1.y);
      float e6 = __expf(bf2f(sv[6]) + Wb[iv[6]] + mk1.z);
      float e7 = __expf(bf2f(sv[7]) + Wb[iv[7]] + mk1.w);
      float sum = e0 + e1 + e2 + e3 + e4 + e5 + e6 + e7;
#pragma unroll
      for (int o = 32; o; o >>= 1) sum += __shfl_xor(sum, o);
      float rinv = 1.f / sum;
      ushort8 ev;
      ev[0] = f2bf(e0); ev[1] = f2bf(e1); ev[2] = f2bf(e2); ev[3] = f2bf(e3);
      ev[4] = f2bf(e4); ev[5] = f2bf(e5); ev[6] = f2bf(e6); ev[7] = f2bf(e7);
      *(ushort8*)(S + row * SWB + lane * 8) = ev;
      if (lane == 0) Rinv[row] = rinv;
    }
  }
  __syncthreads();  // barrier 2: exp(S) bf16, Rinv complete

  // ---- PV (swapped, rotated) + 2-full-row probs writes per iteration ----
  const unsigned short* vptr =
      Vt + ((size_t)(b * Hc + h) * DHc + w * 16 + fr) * Sc;
  float* pbase = probs + (size_t)((b * Hc + h) * Sc + q0) * Sc;
  int prow_half = tid >> 7;          // 0..1 (which of the 2 rows this it)
  int pcol = (tid & 127) * 4;        // 0..508
  f32x4 pacc0 = {}, pacc1 = {};
  bf16x8 vfA0 = *(const bf16x8*)(vptr + rot * 64 + kg8);
  bf16x8 vfA1 = *(const bf16x8*)(vptr + rot * 64 + 32 + kg8);
#pragma unroll
  for (int i = 0; i < 8; ++i) {
    int it = (i + rot) & 7;
    bf16x8 vfB0, vfB1;
    if (i < 7) {
      int itn = (i + 1 + rot) & 7;
      vfB0 = *(const bf16x8*)(vptr + itn * 64 + kg8);
      vfB1 = *(const bf16x8*)(vptr + itn * 64 + 32 + kg8);
    }
    {  // probs: 2 full rows; each wave writes 1 KB contiguous (NT)
      int row = i * 2 + prow_half;
      ushort4 sv = *(const ushort4*)(S + row * SWB + pcol);
      float rv = Rinv[row];
      f32x4 e;
      e[0] = bf2f(sv.x) * rv; e[1] = bf2f(sv.y) * rv;
      e[2] = bf2f(sv.z) * rv; e[3] = bf2f(sv.w) * rv;
      __builtin_nontemporal_store(e, (f32x4*)(pbase + (size_t)row * Sc + pcol));
    }
    bf16x8 pfr0 = *(const bf16x8*)(S + fr * SWB + it * 64 + kg8);
    bf16x8 pfr1 = *(const bf16x8*)(S + fr * SWB + it * 64 + 32 + kg8);
    __builtin_amdgcn_s_setprio(1);
    pacc0 = __builtin_amdgcn_mfma_f32_16x16x32_bf16(vfA0, pfr0, pacc0, 0, 0, 0);
    pacc1 = __builtin_amdgcn_mfma_f32_16x16x32_bf16(vfA1, pfr1, pacc1, 0, 0, 0);
    __builtin_amdgcn_s_setprio(0);
    vfA0 = vfB0; vfA1 = vfB1;
  }

  // ---- ctx epilogue: lane = (q=fr, dh w*16+fq*4..+3) -> one 16B NT store ----
  {
    float rv = Rinv[fr];
    f32x4 o;
    o[0] = (pacc0[0] + pacc1[0]) * rv;
    o[1] = (pacc0[1] + pacc1[1]) * rv;
    o[2] = (pacc0[2] + pacc1[2]) * rv;
    o[3] = (pacc0[3] + pacc1[3]) * rv;
    __builtin_nontemporal_store(
        o, (f32x4*)(ctx + (size_t)(b * Sc + q0 + fr) * Dc + h * DHc + w * 16 + fq * 4));
  }
}

extern "C" void kernel_launch(void* const* d_in, const int* in_sizes, int n_in,
                              void* d_out, int out_size, void* d_ws, size_t ws_size,
                              hipStream_t stream) {
  const float* hidden = (const float*)d_in[0];
  const float* amask = (const float*)d_in[1];
  const int* ind = (const int*)d_in[3];
  const int* outd = (const int*)d_in[4];
  const int* spe = (const int*)d_in[5];
  const float* Wq = (const float*)d_in[8];
  const float* bq = (const float*)d_in[9];
  const float* Wk = (const float*)d_in[10];
  const float* bk = (const float*)d_in[11];
  const float* Wv = (const float*)d_in[12];
  const float* bv = (const float*)d_in[13];
  const float* Win = (const float*)d_in[14];
  const float* Wout = (const float*)d_in[15];
  const float* Wspe = (const float*)d_in[16];

  char* ws = (char*)d_ws;
  const size_t BSD = (size_t)Bc * Sc * Dc;
  unsigned short* hbf = (unsigned short*)ws;                    // 16 MB
  unsigned short* Wtq = (unsigned short*)(ws + 16u * 1048576);  // 2 MB
  unsigned short* Wtk = (unsigned short*)(ws + 18u * 1048576);  // 2 MB
  unsigned short* Wtv = (unsigned short*)(ws + 20u * 1048576);  // 2 MB
  float* WspeT = (float*)(ws + 22u * 1048576);                  // 32 KB
  unsigned short* Qb = (unsigned short*)(ws + 24u * 1048576);   // 16 MB
  unsigned short* Kb = (unsigned short*)(ws + 40u * 1048576);   // 16 MB
  unsigned short* Vt = (unsigned short*)(ws + 56u * 1048576);   // 16 MB (transposed)
  unsigned short* spe16 = (unsigned short*)(ws + 72u * 1048576);  // 8.4 MB
  float* ctx = (float*)d_out;
  float* probs = (float*)d_out + BSD;

  (void)hipFuncSetAttribute((const void*)k_attn,
                            hipFuncAttributeMaxDynamicSharedMemorySize, 18752);

  k_prep<<<dim3(11040), 256, 0, stream>>>(hidden, ind, outd, Win, Wout, Wq, Wk,
                                          Wv, Wspe, spe, hbf, Wtq, Wtk, Wtv,
                                          WspeT, spe16);
  k_gemm_mfma<<<dim3(8, 64, 3), 256, 0, stream>>>(hbf, Wtq, bq, Wtk, bk, Wtv, bv, Qb, Kb, Vt);
  k_attn<<<dim3(8192), 256, 18752, stream>>>(Qb, Kb, Vt, spe16, WspeT, amask, probs, ctx);
}

// Round 25
// 215.163 us; speedup vs baseline: 1.2904x; 1.0574x over previous
//
#include <hip/hip_runtime.h>

#define Bc 16
#define Sc 512
#define Dc 1024
#define Hc 16
#define DHc 64

#define AS1 __attribute__((address_space(1)))
#define AS3 __attribute__((address_space(3)))

typedef __attribute__((ext_vector_type(8))) __bf16 bf16x8;
typedef __attribute__((ext_vector_type(4))) float f32x4;
typedef __attribute__((ext_vector_type(8))) unsigned short ushort8;

static __device__ __forceinline__ unsigned short f2bf(float f) {
  unsigned int u = __builtin_bit_cast(unsigned int, f);
  unsigned int r = (u + 0x7fffu + ((u >> 16) & 1u)) >> 16;  // RNE
  return (unsigned short)r;
}
static __device__ __forceinline__ float bf2f(unsigned short u) {
  unsigned int x = ((unsigned int)u) << 16;
  return __builtin_bit_cast(float, x);
}

// ---------------------------------------------------------------------------
// Merged prep: [0,8192) pos_add ; [8192,8960) W transpose ; [8960,8992) WspeT ;
// [8992,11040) spe int32 -> uint16 pack
// ---------------------------------------------------------------------------
__global__ __launch_bounds__(256) void k_prep(
    const float* __restrict__ hidden, const int* __restrict__ ind,
    const int* __restrict__ outd, const float* __restrict__ Win,
    const float* __restrict__ Wout, const float* __restrict__ Wq,
    const float* __restrict__ Wk, const float* __restrict__ Wv,
    const float* __restrict__ Wspe, const int* __restrict__ spe,
    unsigned short* __restrict__ hbf, unsigned short* __restrict__ Wtq,
    unsigned short* __restrict__ Wtk, unsigned short* __restrict__ Wtv,
    float* __restrict__ WspeT, unsigned short* __restrict__ spe16) {
  __shared__ float tile[64][65];
  int blk = blockIdx.x;
  int t = threadIdx.x;
  if (blk < 8192) {
    int row = blk;
    int id = ind[row], od = outd[row];
    float fi = (id != 0) ? 1.f : 0.f;
    float fo = (od != 0) ? 1.f : 0.f;
    float4 a = ((const float4*)(hidden + (size_t)row * Dc))[t];
    float4 x = ((const float4*)(Win + (size_t)id * Dc))[t];
    float4 y = ((const float4*)(Wout + (size_t)od * Dc))[t];
    ushort4 r;
    r.x = f2bf(a.x + fi * x.x + fo * y.x);
    r.y = f2bf(a.y + fi * x.y + fo * y.y);
    r.z = f2bf(a.z + fi * x.z + fo * y.z);
    r.w = f2bf(a.w + fi * x.w + fo * y.w);
    ((ushort4*)(hbf + (size_t)row * Dc))[t] = r;
  } else if (blk < 8960) {
    int f = blk - 8192;
    int z = f >> 8, rem = f & 255;
    int ky = rem >> 4, nx = rem & 15;
    const float* W = z == 0 ? Wq : z == 1 ? Wk : Wv;
    unsigned short* Wt = z == 0 ? Wtq : z == 1 ? Wtk : Wtv;
    int k0 = ky * 64, n0 = nx * 64;
    int r = t >> 4, c4 = (t & 15) * 4;
    for (int rr = r; rr < 64; rr += 16) {
      float4 v = *(const float4*)(W + (size_t)(k0 + rr) * Dc + n0 + c4);
      tile[rr][c4 + 0] = v.x;
      tile[rr][c4 + 1] = v.y;
      tile[rr][c4 + 2] = v.z;
      tile[rr][c4 + 3] = v.w;
    }
    __syncthreads();
    for (int rr = r; rr < 64; rr += 16) {
      ushort4 o;
      o.x = f2bf(tile[c4 + 0][rr]);
      o.y = f2bf(tile[c4 + 1][rr]);
      o.z = f2bf(tile[c4 + 2][rr]);
      o.w = f2bf(tile[c4 + 3][rr]);
      *(ushort4*)(Wt + (size_t)(n0 + rr) * Dc + k0 + c4) = o;
    }
  } else if (blk < 8992) {
    int idx = (blk - 8960) * 256 + t;
    int h = idx >> 9, i = idx & 511;
    WspeT[idx] = Wspe[i * Hc + h];
  } else {
    size_t base = (size_t)(blk - 8992) * 2048 + t * 8;
    int4 a = *(const int4*)(spe + base);
    int4 c = *(const int4*)(spe + base + 4);
    ushort8 o;
    o[0] = (unsigned short)a.x; o[1] = (unsigned short)a.y;
    o[2] = (unsigned short)a.z; o[3] = (unsigned short)a.w;
    o[4] = (unsigned short)c.x; o[5] = (unsigned short)c.y;
    o[6] = (unsigned short)c.z; o[7] = (unsigned short)c.w;
    *(ushort8*)(spe16 + base) = o;
  }
}

// ---------------------------------------------------------------------------
// QKV projections, bf16 MFMA, BK=64 via split 32-wide LDS halves (proven
// best; ~903 TF). Q pre-scaled by 1/8. V pre-transposed Vt[(b*16+h), dh, s].
// ---------------------------------------------------------------------------
__global__ __launch_bounds__(256) void k_gemm_mfma(
    const unsigned short* __restrict__ hbf,
    const unsigned short* __restrict__ Wtq, const float* __restrict__ bq,
    const unsigned short* __restrict__ Wtk, const float* __restrict__ bk,
    const unsigned short* __restrict__ Wtv, const float* __restrict__ bv,
    unsigned short* __restrict__ Qo, unsigned short* __restrict__ Ko,
    unsigned short* __restrict__ Vt) {
  int zsel = blockIdx.z;
  const unsigned short* Wt;
  const float* bias;
  if (zsel == 0) { Wt = Wtq; bias = bq; }
  else if (zsel == 1) { Wt = Wtk; bias = bk; }
  else { Wt = Wtv; bias = bv; }

  __shared__ __align__(16) unsigned short As0[128 * 32];
  __shared__ __align__(16) unsigned short As1[128 * 32];
  __shared__ __align__(16) unsigned short Bs0[128 * 32];
  __shared__ __align__(16) unsigned short Bs1[128 * 32];

  int tid = threadIdx.x, lane = tid & 63, wave = tid >> 6;
  int m0 = blockIdx.y * 128, n0 = blockIdx.x * 128;
  int wr = wave >> 1, wc = wave & 1;

  f32x4 acc[4][4] = {};

  int srow = lane >> 2;
  int skb = (lane & 3) * 8;
  const unsigned short* gA = hbf + (size_t)(m0 + srow) * Dc + skb;
  const unsigned short* gB = Wt + (size_t)(n0 + srow) * Dc + skb;

  int fr = lane & 15, kg = (lane >> 4) * 8;

  for (int k0 = 0; k0 < Dc; k0 += 64) {
#pragma unroll
    for (int cc = 0; cc < 2; ++cc) {
      int c = wave + cc * 4;  // 16-row chunk id
      __builtin_amdgcn_global_load_lds(
          (const AS1 void*)(gA + (size_t)c * 16 * Dc + k0),
          (AS3 void*)(As0 + c * 16 * 32), 16, 0, 0);
      __builtin_amdgcn_global_load_lds(
          (const AS1 void*)(gA + (size_t)c * 16 * Dc + k0 + 32),
          (AS3 void*)(As1 + c * 16 * 32), 16, 0, 0);
      __builtin_amdgcn_global_load_lds(
          (const AS1 void*)(gB + (size_t)c * 16 * Dc + k0),
          (AS3 void*)(Bs0 + c * 16 * 32), 16, 0, 0);
      __builtin_amdgcn_global_load_lds(
          (const AS1 void*)(gB + (size_t)c * 16 * Dc + k0 + 32),
          (AS3 void*)(Bs1 + c * 16 * 32), 16, 0, 0);
    }
    __syncthreads();

    bf16x8 af[4][2], bfr[4][2];
#pragma unroll
    for (int m = 0; m < 4; ++m) {
      af[m][0] = *(const bf16x8*)(As0 + (wr * 64 + m * 16 + fr) * 32 + kg);
      af[m][1] = *(const bf16x8*)(As1 + (wr * 64 + m * 16 + fr) * 32 + kg);
    }
#pragma unroll
    for (int n = 0; n < 4; ++n) {
      bfr[n][0] = *(const bf16x8*)(Bs0 + (wc * 64 + n * 16 + fr) * 32 + kg);
      bfr[n][1] = *(const bf16x8*)(Bs1 + (wc * 64 + n * 16 + fr) * 32 + kg);
    }
#pragma unroll
    for (int m = 0; m < 4; ++m)
#pragma unroll
      for (int n = 0; n < 4; ++n) {
        acc[m][n] = __builtin_amdgcn_mfma_f32_16x16x32_bf16(af[m][0], bfr[n][0], acc[m][n], 0, 0, 0);
        acc[m][n] = __builtin_amdgcn_mfma_f32_16x16x32_bf16(af[m][1], bfr[n][1], acc[m][n], 0, 0, 0);
      }
    __syncthreads();
  }

  int fq = lane >> 4;
  if (zsel < 2) {
    unsigned short* C = (zsel == 0) ? Qo : Ko;
    float scale = (zsel == 0) ? 0.125f : 1.f;  // fold 1/sqrt(64) into Q (exact)
#pragma unroll
    for (int m = 0; m < 4; ++m) {
#pragma unroll
      for (int n = 0; n < 4; ++n) {
        int col = n0 + wc * 64 + n * 16 + fr;
        float bb = bias[col];
#pragma unroll
        for (int r = 0; r < 4; ++r) {
          int row = m0 + wr * 64 + m * 16 + fq * 4 + r;
          C[(size_t)row * Dc + col] = f2bf((acc[m][n][r] + bb) * scale);
        }
      }
    }
  } else {
#pragma unroll
    for (int m = 0; m < 4; ++m) {
#pragma unroll
      for (int n = 0; n < 4; ++n) {
        int col = n0 + wc * 64 + n * 16 + fr;
        int hh = col >> 6, dh = col & 63;
        float bb = bias[col];
        int row = m0 + wr * 64 + m * 16 + fq * 4;
        int bb_ = row >> 9, ss = row & 511;
        ushort4 pk;
        pk.x = f2bf(acc[m][n][0] + bb);
        pk.y = f2bf(acc[m][n][1] + bb);
        pk.z = f2bf(acc[m][n][2] + bb);
        pk.w = f2bf(acc[m][n][3] + bb);
        *(ushort4*)(Vt + ((size_t)(bb_ * Hc + hh) * DHc + dh) * Sc + ss) = pk;
      }
    }
  }
}

// ---------------------------------------------------------------------------
// Fused attention, QB=32: block = (b, h, 32 q-rows); 4 waves; LDS 35456 B
// -> 4 blocks/CU (16 waves). Halves block count (4096): per-block overhead
// amortized 2x, K/V L2 re-read pressure halved, probs bursts 2KB/wave.
// Same per-element math as QB=16 config (bit-identical numerics).
// ---------------------------------------------------------------------------
#define SWB 520
__global__ __launch_bounds__(256, 4) void k_attn(
    const unsigned short* __restrict__ Qb, const unsigned short* __restrict__ Kb,
    const unsigned short* __restrict__ Vt, const unsigned short* __restrict__ spe16,
    const float* __restrict__ WspeT, const float* __restrict__ mask,
    float* __restrict__ probs, float* __restrict__ ctx) {
  extern __shared__ char smem[];
  unsigned short* S = (unsigned short*)smem;     // 32*520*2 = 33280
  float* Wb = (float*)(smem + 33280);            // 2048
  float* Rinv = (float*)(smem + 33280 + 2048);   // 128

  int tid = threadIdx.x, lane = tid & 63, w = tid >> 6;
  int fr = lane & 15, fq = lane >> 4, kg8 = fq * 8;

  // L2-capacity swizzle: xcd = (b&3)*2 + (h>>3); h-innermost within idx.
  int flat = blockIdx.x;                  // 4096 blocks
  int xcd = flat & 7, idx = flat >> 3;    // idx < 512
  int b = (idx >> 7) * 4 + (xcd >> 1);
  int h = (xcd & 1) * 8 + (idx & 7);
  int qt = (idx >> 3) & 15;
  int q0 = qt * 32;
  int rot = idx & 7;

  // coalesced per-head bias row
  for (int i = tid; i < 512; i += 256) Wb[i] = WspeT[h * 512 + i];

  float4 mk0 = *(const float4*)(mask + b * Sc + lane * 8);
  float4 mk1 = *(const float4*)(mask + b * Sc + lane * 8 + 4);

  // Q fragments (pre-scaled by 1/8): 2 q-halves x 2 k-subtiles
  const unsigned short* qbase = Qb + (size_t)(b * Sc + q0) * Dc + h * DHc;
  bf16x8 af[2][2];
#pragma unroll
  for (int qh = 0; qh < 2; ++qh)
#pragma unroll
    for (int kk = 0; kk < 2; ++kk)
      af[qh][kk] = *(const bf16x8*)(qbase + (size_t)(qh * 16 + fr) * Dc + kk * 32 + kg8);

  // ---- QK^T (swapped, rotated): 4 MFMAs/iter (2 q-halves) ----
  const unsigned short* kptr =
      Kb + (size_t)(b * Sc + w * 16 + fr) * Dc + h * DHc;
  bf16x8 kfA0 = *(const bf16x8*)(kptr + (size_t)rot * 64 * Dc + kg8);
  bf16x8 kfA1 = *(const bf16x8*)(kptr + (size_t)rot * 64 * Dc + 32 + kg8);
#pragma unroll
  for (int i = 0; i < 8; ++i) {
    int it = (i + rot) & 7;
    bf16x8 kfB0, kfB1;
    if (i < 7) {
      int itn = (i + 1 + rot) & 7;
      const unsigned short* np = kptr + (size_t)itn * 64 * Dc;
      kfB0 = *(const bf16x8*)(np + kg8);
      kfB1 = *(const bf16x8*)(np + 32 + kg8);
    }
    f32x4 acc0 = {}, acc1 = {};
    __builtin_amdgcn_s_setprio(1);
    acc0 = __builtin_amdgcn_mfma_f32_16x16x32_bf16(kfA0, af[0][0], acc0, 0, 0, 0);
    acc0 = __builtin_amdgcn_mfma_f32_16x16x32_bf16(kfA1, af[0][1], acc0, 0, 0, 0);
    acc1 = __builtin_amdgcn_mfma_f32_16x16x32_bf16(kfA0, af[1][0], acc1, 0, 0, 0);
    acc1 = __builtin_amdgcn_mfma_f32_16x16x32_bf16(kfA1, af[1][1], acc1, 0, 0, 0);
    __builtin_amdgcn_s_setprio(0);
    ushort4 pk0, pk1;
    pk0.x = f2bf(acc0[0]); pk0.y = f2bf(acc0[1]);
    pk0.z = f2bf(acc0[2]); pk0.w = f2bf(acc0[3]);
    pk1.x = f2bf(acc1[0]); pk1.y = f2bf(acc1[1]);
    pk1.z = f2bf(acc1[2]); pk1.w = f2bf(acc1[3]);
    *(ushort4*)(S + fr * SWB + it * 64 + w * 16 + fq * 4) = pk0;
    *(ushort4*)(S + (16 + fr) * SWB + it * 64 + w * 16 + fq * 4) = pk1;
    kfA0 = kfB0; kfA1 = kfB1;
  }
  __syncthreads();  // barrier 1: S complete, Wb ready

  // ---- softmax (no max-subtract): 8 rows per wave ----
  {
    const unsigned short* spp0 =
        spe16 + (size_t)(b * Sc + q0 + w * 8) * Sc + lane * 8;
#pragma unroll
    for (int r8 = 0; r8 < 8; ++r8) {
      int row = w * 8 + r8;
      ushort8 iv = *(const ushort8*)(spp0 + (size_t)r8 * Sc);
      ushort8 sv = *(const ushort8*)(S + row * SWB + lane * 8);
      float e0 = __expf(bf2f(sv[0]) + Wb[iv[0]] + mk0.x);
      float e1 = __expf(bf2f(sv[1]) + Wb[iv[1]] + mk0.y);
      float e2 = __expf(bf2f(sv[2]) + Wb[iv[2]] + mk0.z);
      float e3 = __expf(bf2f(sv[3]) + Wb[iv[3]] + mk0.w);
      float e4 = __expf(bf2f(sv[4]) + Wb[iv[4]] + mk1.x);
      float e5 = __expf(bf2f(sv[5]) + Wb[iv[5]] + mk1.y);
      float e6 = __expf(bf2f(sv[6]) + Wb[iv[6]] + mk1.z);
      float e7 = __expf(bf2f(sv[7]) + Wb[iv[7]] + mk1.w);
      float sum = e0 + e1 + e2 + e3 + e4 + e5 + e6 + e7;
#pragma unroll
      for (int o = 32; o; o >>= 1) sum += __shfl_xor(sum, o);
      float rinv = 1.f / sum;
      ushort8 ev;
      ev[0] = f2bf(e0); ev[1] = f2bf(e1); ev[2] = f2bf(e2); ev[3] = f2bf(e3);
      ev[4] = f2bf(e4); ev[5] = f2bf(e5); ev[6] = f2bf(e6); ev[7] = f2bf(e7);
      *(ushort8*)(S + row * SWB + lane * 8) = ev;
      if (lane == 0) Rinv[row] = rinv;
    }
  }
  __syncthreads();  // barrier 2: exp(S) bf16, Rinv complete

  // ---- PV (swapped, rotated): 4 MFMAs/iter + 1-full-row-per-wave probs ----
  const unsigned short* vptr =
      Vt + ((size_t)(b * Hc + h) * DHc + w * 16 + fr) * Sc;
  float* pbase = probs + (size_t)((b * Hc + h) * Sc + q0) * Sc;
  f32x4 pacc00 = {}, pacc01 = {}, pacc10 = {}, pacc11 = {};
  bf16x8 vfA0 = *(const bf16x8*)(vptr + rot * 64 + kg8);
  bf16x8 vfA1 = *(const bf16x8*)(vptr + rot * 64 + 32 + kg8);
#pragma unroll
  for (int i = 0; i < 8; ++i) {
    int it = (i + rot) & 7;
    bf16x8 vfB0, vfB1;
    if (i < 7) {
      int itn = (i + 1 + rot) & 7;
      vfB0 = *(const bf16x8*)(vptr + itn * 64 + kg8);
      vfB1 = *(const bf16x8*)(vptr + itn * 64 + 32 + kg8);
    }
    {  // probs: each wave writes one full row (2 KB contiguous NT)
      int row = i * 4 + w;
      ushort8 sv = *(const ushort8*)(S + row * SWB + lane * 8);
      float rv = Rinv[row];
      f32x4 e0, e1;
      e0[0] = bf2f(sv[0]) * rv; e0[1] = bf2f(sv[1]) * rv;
      e0[2] = bf2f(sv[2]) * rv; e0[3] = bf2f(sv[3]) * rv;
      e1[0] = bf2f(sv[4]) * rv; e1[1] = bf2f(sv[5]) * rv;
      e1[2] = bf2f(sv[6]) * rv; e1[3] = bf2f(sv[7]) * rv;
      float* pdst = pbase + (size_t)row * Sc + lane * 8;
      __builtin_nontemporal_store(e0, (f32x4*)pdst);
      __builtin_nontemporal_store(e1, (f32x4*)(pdst + 4));
    }
    bf16x8 p00 = *(const bf16x8*)(S + fr * SWB + it * 64 + kg8);
    bf16x8 p01 = *(const bf16x8*)(S + fr * SWB + it * 64 + 32 + kg8);
    bf16x8 p10 = *(const bf16x8*)(S + (16 + fr) * SWB + it * 64 + kg8);
    bf16x8 p11 = *(const bf16x8*)(S + (16 + fr) * SWB + it * 64 + 32 + kg8);
    __builtin_amdgcn_s_setprio(1);
    pacc00 = __builtin_amdgcn_mfma_f32_16x16x32_bf16(vfA0, p00, pacc00, 0, 0, 0);
    pacc01 = __builtin_amdgcn_mfma_f32_16x16x32_bf16(vfA1, p01, pacc01, 0, 0, 0);
    pacc10 = __builtin_amdgcn_mfma_f32_16x16x32_bf16(vfA0, p10, pacc10, 0, 0, 0);
    pacc11 = __builtin_amdgcn_mfma_f32_16x16x32_bf16(vfA1, p11, pacc11, 0, 0, 0);
    __builtin_amdgcn_s_setprio(0);
    vfA0 = vfB0; vfA1 = vfB1;
  }

  // ---- ctx epilogue: 2 q-halves, one 16B NT store each ----
#pragma unroll
  for (int qh = 0; qh < 2; ++qh) {
    float rv = Rinv[qh * 16 + fr];
    f32x4 a0 = (qh == 0) ? pacc00 : pacc10;
    f32x4 a1 = (qh == 0) ? pacc01 : pacc11;
    f32x4 o;
    o[0] = (a0[0] + a1[0]) * rv;
    o[1] = (a0[1] + a1[1]) * rv;
    o[2] = (a0[2] + a1[2]) * rv;
    o[3] = (a0[3] + a1[3]) * rv;
    __builtin_nontemporal_store(
        o, (f32x4*)(ctx + (size_t)(b * Sc + q0 + qh * 16 + fr) * Dc + h * DHc + w * 16 + fq * 4));
  }
}

extern "C" void kernel_launch(void* const* d_in, const int* in_sizes, int n_in,
                              void* d_out, int out_size, void* d_ws, size_t ws_size,
                              hipStream_t stream) {
  const float* hidden = (const float*)d_in[0];
  const float* amask = (const float*)d_in[1];
  const int* ind = (const int*)d_in[3];
  const int* outd = (const int*)d_in[4];
  const int* spe = (const int*)d_in[5];
  const float* Wq = (const float*)d_in[8];
  const float* bq = (const float*)d_in[9];
  const float* Wk = (const float*)d_in[10];
  const float* bk = (const float*)d_in[11];
  const float* Wv = (const float*)d_in[12];
  const float* bv = (const float*)d_in[13];
  const float* Win = (const float*)d_in[14];
  const float* Wout = (const float*)d_in[15];
  const float* Wspe = (const float*)d_in[16];

  char* ws = (char*)d_ws;
  const size_t BSD = (size_t)Bc * Sc * Dc;
  unsigned short* hbf = (unsigned short*)ws;                    // 16 MB
  unsigned short* Wtq = (unsigned short*)(ws + 16u * 1048576);  // 2 MB
  unsigned short* Wtk = (unsigned short*)(ws + 18u * 1048576);  // 2 MB
  unsigned short* Wtv = (unsigned short*)(ws + 20u * 1048576);  // 2 MB
  float* WspeT = (float*)(ws + 22u * 1048576);                  // 32 KB
  unsigned short* Qb = (unsigned short*)(ws + 24u * 1048576);   // 16 MB
  unsigned short* Kb = (unsigned short*)(ws + 40u * 1048576);   // 16 MB
  unsigned short* Vt = (unsigned short*)(ws + 56u * 1048576);   // 16 MB (transposed)
  unsigned short* spe16 = (unsigned short*)(ws + 72u * 1048576);  // 8.4 MB
  float* ctx = (float*)d_out;
  float* probs = (float*)d_out + BSD;

  (void)hipFuncSetAttribute((const void*)k_attn,
                            hipFuncAttributeMaxDynamicSharedMemorySize, 35456);

  k_prep<<<dim3(11040), 256, 0, stream>>>(hidden, ind, outd, Win, Wout, Wq, Wk,
                                          Wv, Wspe, spe, hbf, Wtq, Wtk, Wtv,
                                          WspeT, spe16);
  k_gemm_mfma<<<dim3(8, 64, 3), 256, 0, stream>>>(hbf, Wtq, bq, Wtk, bk, Wtv, bv, Qb, Kb, Vt);
  k_attn<<<dim3(4096), 256, 35456, stream>>>(Qb, Kb, Vt, spe16, WspeT, amask, probs, ctx);
}